// Round 1
// baseline (611.671 us; speedup 1.0000x reference)
//
#include <hip/hip_runtime.h>
#include <math.h>

// SparseNet: conv1(2x2,200->16,pad(0,1)) * mask -> maskedpool 3x3/3 ->
// conv2(5x5,16->32,VALID) * pooledmask -> maskedpool 3x3/1 -> linear(32,2) -> softmax
// B=1024, H=W=21, Cin=200.

#define NEGINF -1e30f

// Order-preserving float<->int map so masked max-pool can run as LDS atomicMax.
__device__ __forceinline__ int f2o(float f) {
    int i = __float_as_int(f);
    return (i >= 0) ? i : (i ^ 0x7FFFFFFF);
}
__device__ __forceinline__ float o2f(int o) {
    return __int_as_float((o >= 0) ? o : (o ^ 0x7FFFFFFF));
}

// ---------------- Kernel A: conv1 + mask + masked maxpool (21 -> 7) ----------------
// 2 batches per block, 512 threads, grid = 512.
// LDS: W1 (51.2 KB) + masks + active-site worklist + pooled accumulators (~59 KB)
// -> 2 blocks/CU, 16 waves/CU at <=128 VGPRs.
__global__ __launch_bounds__(512, 4) void conv1_pool_kernel(
    const float* __restrict__ x,     // [1024,21,21,200]
    const int*   __restrict__ mask,  // [1024,21,21]
    const float* __restrict__ W1,    // [2,2,200,16]
    float* __restrict__ h2,          // [1024,49,16]
    float* __restrict__ m2)          // [1024,49]
{
    __shared__ float w1s[4 * 200 * 16];        // 51.2 KB, same layout as global W1
    __shared__ unsigned char msk[2 * 441];
    __shared__ unsigned short act[2 * 441];    // compacted active-site list
    __shared__ int h2ord[2][49][16];           // pool accumulators (ordered-int max)
    __shared__ int nact;

    const int t  = threadIdx.x;
    const int b0 = blockIdx.x * 2;

    // ---- stage weights into LDS (coalesced float4) ----
    {
        const float4* __restrict__ wg = (const float4*)W1;
        float4* wl = (float4*)w1s;
        for (int v = t; v < 3200; v += 512) wl[v] = wg[v];
    }
    if (t == 0) nact = 0;
    for (int v = t; v < 2 * 49 * 16; v += 512) ((int*)h2ord)[v] = 0x80000000; // INT_MIN
    __syncthreads();

    // ---- stage masks + compact active sites ----
    for (int v = t; v < 2 * 441; v += 512) {
        const int b2 = (v >= 441) ? 1 : 0;
        const int p  = v - b2 * 441;
        const int mv = mask[(size_t)(b0 + b2) * 441 + p];
        msk[v] = (unsigned char)(mv != 0);
        if (mv != 0) {
            const int idx = atomicAdd(&nact, 1);
            act[idx] = (unsigned short)v;
        }
    }
    __syncthreads();

    // ---- conv1 at active sites (packed waves), fused masked max-pool via atomicMax ----
    const int na = nact;
    for (int idx = t; idx < na; idx += 512) {
        const int u  = act[idx];
        const int b2 = (u >= 441) ? 1 : 0;
        const int p  = u - b2 * 441;
        const int i  = p / 21;
        const int j  = p - i * 21;
        const float* __restrict__ xb = x + (size_t)(b0 + b2) * 441 * 200;

        float acc[16];
        #pragma unroll
        for (int c = 0; c < 16; ++c) acc[c] = 0.0f;

        #pragma unroll
        for (int tap = 0; tap < 4; ++tap) {
            const int ii = i + (tap >> 1);
            const int jj = j + (tap & 1);
            // pad (0,1): ii==21 / jj==21 is zero padding; inactive input sites contribute 0
            if (ii < 21 && jj < 21 && msk[b2 * 441 + ii * 21 + jj]) {
                const float4* __restrict__ xp = (const float4*)(xb + (ii * 21 + jj) * 200);
                const float4* wp = ((const float4*)w1s) + tap * 800;  // wave-uniform LDS broadcast

                #pragma unroll 2
                for (int k4 = 0; k4 < 50; ++k4) {
                    const float4 xv = xp[k4];
                    #pragma unroll
                    for (int q = 0; q < 4; ++q) {
                        const float xs = (q == 0) ? xv.x : (q == 1) ? xv.y
                                       : (q == 2) ? xv.z : xv.w;
                        const int kb = (k4 * 4 + q) * 4;
                        const float4 w0 = wp[kb + 0];
                        const float4 w1 = wp[kb + 1];
                        const float4 w2 = wp[kb + 2];
                        const float4 w3 = wp[kb + 3];
                        acc[0]  = fmaf(xs, w0.x, acc[0]);
                        acc[1]  = fmaf(xs, w0.y, acc[1]);
                        acc[2]  = fmaf(xs, w0.z, acc[2]);
                        acc[3]  = fmaf(xs, w0.w, acc[3]);
                        acc[4]  = fmaf(xs, w1.x, acc[4]);
                        acc[5]  = fmaf(xs, w1.y, acc[5]);
                        acc[6]  = fmaf(xs, w1.z, acc[6]);
                        acc[7]  = fmaf(xs, w1.w, acc[7]);
                        acc[8]  = fmaf(xs, w2.x, acc[8]);
                        acc[9]  = fmaf(xs, w2.y, acc[9]);
                        acc[10] = fmaf(xs, w2.z, acc[10]);
                        acc[11] = fmaf(xs, w2.w, acc[11]);
                        acc[12] = fmaf(xs, w3.x, acc[12]);
                        acc[13] = fmaf(xs, w3.y, acc[13]);
                        acc[14] = fmaf(xs, w3.z, acc[14]);
                        acc[15] = fmaf(xs, w3.w, acc[15]);
                    }
                }
            }
        }

        // every pixel belongs to exactly one 3x3/3 window (21 = 7*3); site is active
        const int cell = (i / 3) * 7 + (j / 3);
        int* dst = &h2ord[b2][cell][0];
        #pragma unroll
        for (int c = 0; c < 16; ++c) atomicMax(&dst[c], f2o(acc[c]));
    }
    __syncthreads();

    // ---- write pooled output + pooled mask ----
    for (int v = t; v < 2 * 49 * 16; v += 512) {
        const int b2   = (v >= 784) ? 1 : 0;
        const int r    = v - b2 * 784;
        const int cell = r >> 4;
        const int ch   = r & 15;
        const int pr = cell / 7, pc = cell - pr * 7;
        const unsigned char* mrow = &msk[b2 * 441 + (pr * 3) * 21 + pc * 3];
        int any = 0;
        #pragma unroll
        for (int rr = 0; rr < 3; ++rr)
            any |= mrow[rr * 21 + 0] | mrow[rr * 21 + 1] | mrow[rr * 21 + 2];
        const float val = any ? o2f(h2ord[b2][cell][ch]) : 0.0f;
        h2[(size_t)((b0 + b2) * 49 + cell) * 16 + ch] = val;
        if (ch == 0) m2[(b0 + b2) * 49 + cell] = any ? 1.0f : 0.0f;
    }
}

// ---------------- Kernel B: conv2 + mask + final masked pool + linear + softmax ----------------
// grid = 1024, block = 256. (unchanged — verified correct previously)
__global__ __launch_bounds__(256) void tail_kernel(
    const float* __restrict__ h2,    // [1024,49,16]
    const float* __restrict__ m2,    // [1024,49]
    const float* __restrict__ W2,    // [5,5,16,32]
    const float* __restrict__ Wlin,  // [32,2]
    const float* __restrict__ blin,  // [2]
    float* __restrict__ out)         // [1024,2]
{
    __shared__ float h2s[49][16];
    __shared__ float m2s[49];
    __shared__ float hc[9][32];
    __shared__ float m3s[9];
    __shared__ float h4[32];

    const int b = blockIdx.x;
    const int t = threadIdx.x;

    for (int t2 = t; t2 < 784; t2 += 256)
        h2s[t2 >> 4][t2 & 15] = h2[(size_t)b * 784 + t2];
    if (t < 49) m2s[t] = m2[b * 49 + t];
    __syncthreads();

    // conv2: 7x7 -> 3x3, 16 -> 32 channels; gate by 5x5 mask-pool
    for (int t2 = t; t2 < 288; t2 += 256) {
        const int cell = t2 >> 5;        // 0..8
        const int oc   = t2 & 31;
        const int ci = cell / 3, cj = cell - ci * 3;
        float acc = 0.0f;
        float mm = 0.0f;
        #pragma unroll
        for (int di = 0; di < 5; ++di) {
            #pragma unroll
            for (int dj = 0; dj < 5; ++dj) {
                const int s = (ci + di) * 7 + (cj + dj);
                mm = fmaxf(mm, m2s[s]);
                const float* __restrict__ wrow = W2 + ((di * 5 + dj) * 16) * 32 + oc;
                #pragma unroll
                for (int c = 0; c < 16; ++c)
                    acc = fmaf(h2s[s][c], wrow[c * 32], acc);
            }
        }
        hc[cell][oc] = (mm > 0.0f) ? acc : 0.0f;
        if (oc == 0) m3s[cell] = mm;
    }
    __syncthreads();

    // final masked maxpool 3x3 stride 1 on 3x3 -> 1x1 (window covers all 9 cells)
    if (t < 32) {
        float best = NEGINF;
        bool any = false;
        #pragma unroll
        for (int cell = 0; cell < 9; ++cell) {
            if (m3s[cell] > 0.0f) {
                any = true;
                best = fmaxf(best, hc[cell][t]);
            }
        }
        h4[t] = any ? best : 0.0f;
    }
    __syncthreads();

    if (t == 0) {
        float l0 = blin[0], l1 = blin[1];
        #pragma unroll
        for (int c = 0; c < 32; ++c) {
            l0 = fmaf(h4[c], Wlin[c * 2 + 0], l0);
            l1 = fmaf(h4[c], Wlin[c * 2 + 1], l1);
        }
        const float mx = fmaxf(l0, l1);
        const float e0 = expf(l0 - mx);
        const float e1 = expf(l1 - mx);
        const float inv = 1.0f / (e0 + e1);
        out[b * 2 + 0] = e0 * inv;
        out[b * 2 + 1] = e1 * inv;
    }
}

extern "C" void kernel_launch(void* const* d_in, const int* in_sizes, int n_in,
                              void* d_out, int out_size, void* d_ws, size_t ws_size,
                              hipStream_t stream) {
    const float* x    = (const float*)d_in[0];
    const int*   mask = (const int*)d_in[1];
    const float* W1   = (const float*)d_in[2];
    const float* W2   = (const float*)d_in[3];
    const float* Wlin = (const float*)d_in[4];
    const float* blin = (const float*)d_in[5];
    float* out = (float*)d_out;

    float* h2 = (float*)d_ws;                  // 1024*49*16 floats = 3.21 MB
    float* m2 = h2 + 1024 * 49 * 16;           // 1024*49 floats

    conv1_pool_kernel<<<512, 512, 0, stream>>>(x, mask, W1, h2, m2);
    tail_kernel<<<1024, 256, 0, stream>>>(h2, m2, W2, Wlin, blin, out);
}